// Round 2
// baseline (916.651 us; speedup 1.0000x reference)
//
#include <hip/hip_runtime.h>
#include <math.h>

#define NLVL 16
#define TSIZE 16384

typedef float floatx4 __attribute__((ext_vector_type(4)));

struct NsArg { float nf[NLVL]; };

__global__ __launch_bounds__(256) void hashgrid_enc(
    const float* __restrict__ inp,
    const float2* __restrict__ tbl,
    float* __restrict__ out,
    NsArg ns, int npts)
{
    int n = blockIdx.x * 256 + threadIdx.x;
    if (n >= npts) return;
    const unsigned P1 = 2654435761u, P2 = 805459861u;

    float x0 = (inp[3*n+0] + 3.0f) / 6.0f;
    float x1 = (inp[3*n+1] + 3.0f) / 6.0f;
    float x2 = (inp[3*n+2] + 3.0f) / 6.0f;

    float res[2*NLVL];

#pragma unroll
    for (int l = 0; l < NLVL; ++l) {
        const float Nf = ns.nf[l];
        float t0 = x0 * Nf, t1 = x1 * Nf, t2 = x2 * Nf;
        float fl0 = floorf(t0), fl1 = floorf(t1), fl2 = floorf(t2);
        float p0 = t0 - fl0, p1 = t1 - fl1, p2 = t2 - fl2;
        unsigned m0 = (unsigned)fl0, m1 = (unsigned)fl1, m2 = (unsigned)fl2;
        unsigned a0 = m0,      a1 = m0 + 1u;
        unsigned b0 = m1 * P1, b1 = b0 + P1;
        unsigned c0 = m2 * P2, c1 = c0 + P2;
        float q0 = 1.0f - p0, q1 = 1.0f - p1, q2 = 1.0f - p2;
        float w00 = q0*q1, w01 = q0*p1, w10 = p0*q1, w11 = p0*p1;
        const float2* tl = tbl + l*TSIZE;
        float acc0 = 0.0f, acc1 = 0.0f;
        // corner c: coord bits (dim0 = c>>2&1, dim1 = c>>1&1, dim2 = c&1)
#define CORNER(A,B,C,WXY,WZ) { unsigned idx = ((A)^(B)^(C)) & (TSIZE-1); \
        float2 g = tl[idx]; float w = (WXY)*(WZ); \
        acc0 = fmaf(w, g.x, acc0); acc1 = fmaf(w, g.y, acc1); }
        CORNER(a0, b0, c0, w00, q2)
        CORNER(a0, b0, c1, w00, p2)
        CORNER(a0, b1, c0, w01, q2)
        CORNER(a0, b1, c1, w01, p2)
        CORNER(a1, b0, c0, w10, q2)
        CORNER(a1, b0, c1, w10, p2)
        CORNER(a1, b1, c0, w11, q2)
        CORNER(a1, b1, c1, w11, p2)
#undef CORNER
        res[2*l]   = acc0;
        res[2*l+1] = acc1;
    }

    floatx4* o = (floatx4*)(out + (size_t)n * (2*NLVL));
    const floatx4* r = (const floatx4*)res;
#pragma unroll
    for (int j = 0; j < 8; ++j)
        __builtin_nontemporal_store(r[j], o + j);
}

extern "C" void kernel_launch(void* const* d_in, const int* in_sizes, int n_in,
                              void* d_out, int out_size, void* d_ws, size_t ws_size,
                              hipStream_t stream) {
    const float*  inp = (const float*)d_in[0];
    const float2* tbl = (const float2*)d_in[1];
    float* out = (float*)d_out;

    // Reproduce NS = [int(16 * b**i)] with the SAME libm CPython uses on this
    // host (values sit ~1e-14 from exact powers of 2 at i=3,6,9,12,15 — must
    // truncate identically).
    NsArg ns;
    double b = exp((log(512.0) - log(16.0)) / 15.0);
    for (int i = 0; i < NLVL; ++i)
        ns.nf[i] = (float)(int)(16.0 * pow(b, (double)i));

    int npts = in_sizes[0] / 3;
    int blocks = (npts + 255) / 256;
    hashgrid_enc<<<dim3(blocks), dim3(256), 0, stream>>>(inp, tbl, out, ns, npts);
}